// Round 12
// baseline (163.666 us; speedup 1.0000x reference)
//
#include <hip/hip_runtime.h>

#define BATCH 16
#define CCH   256
#define WLEN  4096
#define OCH   256
#define KW    3
#define CK    768      // CCH*KW
#define WIN   96       // x-window floats per channel
#define CHUNK 32       // channels per K-chunk
#define NCHUNK 8       // CCH / CHUNK
#define SLD   104      // Sl row stride (shorts): 96 ck + 8 pad, keeps 16B align (v11 layout;
                       // v12's odd-stride experiment RAISED conflicts 5.16M->7.52M, reverted)

typedef short bf16x8 __attribute__((ext_vector_type(8)));
typedef unsigned u32x2 __attribute__((ext_vector_type(2)));
typedef float f32x4  __attribute__((ext_vector_type(4)));

__device__ inline short f2bf(float f) {
    union { float f; unsigned u; } v; v.f = f;
    unsigned r = v.u + 0x7FFFu + ((v.u >> 16) & 1u);   // RNE
    return (short)(r >> 16);
}

// packed RNE f32x2 -> bf16x2 in ONE VALU op (compiler can't derive this from bit-math)
__device__ inline unsigned pk2(float a, float b) {
    unsigned r;
    asm("v_cvt_pk_bf16_f32 %0, %1, %2" : "=v"(r) : "v"(a), "v"(b));
    return r;
}

__device__ inline void gl_lds16(const void* g, void* l) {
    __builtin_amdgcn_global_load_lds(
        (const __attribute__((address_space(1))) unsigned int*)g,
        (__attribute__((address_space(3))) unsigned int*)l, 16, 0, 0);
}

template<int N> __device__ inline void vmwait() {
    if constexpr (N == 0)      asm volatile("s_waitcnt vmcnt(0)" ::: "memory");
    else if constexpr (N == 1) asm volatile("s_waitcnt vmcnt(1)" ::: "memory");
    else if constexpr (N == 2) asm volatile("s_waitcnt vmcnt(2)" ::: "memory");
    else if constexpr (N == 4) asm volatile("s_waitcnt vmcnt(4)" ::: "memory");
    else if constexpr (N == 6) asm volatile("s_waitcnt vmcnt(6)" ::: "memory");
    else if constexpr (N == 7) asm volatile("s_waitcnt vmcnt(7)" ::: "memory");
    else if constexpr (N == 8) asm volatile("s_waitcnt vmcnt(8)" ::: "memory");
}
__device__ inline void lgkm0() { asm volatile("s_waitcnt lgkmcnt(0)" ::: "memory"); }

// ---------------- kernel 1: weight fp32 [256][768] -> bf16 ----------------
__global__ void wconv_kernel(const float* __restrict__ w, short* __restrict__ wb) {
    int i = blockIdx.x * 256 + threadIdx.x;
    wb[i] = f2bf(w[i]);
}

// ---------------- fused kernel v13: v11 pipeline + cvt_pk gather ----------------
// EXACT v11 choreography (71.6 us best: tail-issued loadA/stage, full-flight DMA).
// One change: gather's convert+pack path. Manual RNE f2bf + short-packing (~5 VALU
// per sample) -> v_cvt_pk_bf16_f32 (1 VALU per PAIR, outputs pre-packed dwords).
// v12 measured VALUBusy:dur ~1:1 at the margin -> expect ~-1k VALU cyc/CU-chunk.
__global__ __launch_bounds__(512, 4)
void deform_fused_kernel(const float* __restrict__ x,
                         const short* __restrict__ wb,
                         const float* __restrict__ off,
                         const float* __restrict__ msk,
                         const float* __restrict__ bias,
                         float* __restrict__ out) {
    __shared__ float WinS[3][CHUNK * WIN];   // 3 x 12288 B: chunk windows
    __shared__ short SlS[2][64 * SLD];       // 2 x 13312 B: gathered B-tile [w][96ck]

    const int t      = threadIdx.x;
    const int b      = blockIdx.x >> 6;
    const int wt     = blockIdx.x & 63;
    const int lane   = t & 63;
    const int wv     = t >> 6;
    const int lr     = lane & 15;
    const int lq     = lane >> 4;
    const int wstart = wt * 64 - 16;
    const int wg     = wt * 64 + lane;

    // ---- per-lane sampling params (identical math to validated kernel) ----
    int   li[3];
    float rw0[3], rw1[3];
#pragma unroll
    for (int k = 0; k < 3; ++k) {
        float o  = off[b * (KW * WLEN) + k * WLEN + wg];
        float m  = msk[b * (KW * WLEN) + k * WLEN + wg];
        float p  = (float)(wg - 1 + k) + o;
        float pf = floorf(p);
        float w1 = p - pf;
        int i0 = (int)pf;
        int i1 = i0 + 1;
        bool v0 = (i0 >= 0) & (i0 < WLEN);
        bool v1 = (i1 >= 0) & (i1 < WLEN);
        li[k]  = min(max(i0 - wstart, 0), WIN - 2);   // row[li], row[li+1] both in-window
        rw0[k] = v0 ? m * (1.0f - w1) : 0.0f;
        rw1[k] = v1 ? m * w1 : 0.0f;
    }

    const float* xb = x + (size_t)b * CCH * WLEN;

    // ---- staging source offsets (lane-static): 768 float4 slots per chunk ----
    const int sA = t;
    const int chA = sA / 24, oA = sA - chA * 24;
    const int jA  = min(max(wstart + oA * 4, 0), WLEN - 4);
    const int offA = chA * WLEN + jA;
    const int sB = 512 + t;
    const int chB = sB / 24, oB = sB - chB * 24;
    const int jB  = min(max(wstart + oB * 4, 0), WLEN - 4);
    const int offB = chB * WLEN + jB;

    f32x4 acc[2][4];
#pragma unroll
    for (int i = 0; i < 2; ++i)
#pragma unroll
        for (int j = 0; j < 4; ++j)
            acc[i][j] = (f32x4){0.f, 0.f, 0.f, 0.f};

    // ---- stage chunk c's windows into WinS[bufsel] (waves 0-3: 2 DMA, 4-7: 1 DMA) ----
    auto stage = [&](int c, int bufsel) {
        const float* src = xb + (size_t)c * CHUNK * WLEN;
        gl_lds16(src + offA, &WinS[bufsel][wv * 256]);
        if (wv < 4) gl_lds16(src + offB, &WinS[bufsel][2048 + wv * 256]);
    };

    // ---- gather: sample 12 values (ds_read2-mergeable taps), cvt_pk, 3 b64 writes ----
    auto gather = [&](int wbuf, int sbuf) {
        float sv[12];
#pragma unroll
        for (int dc = 0; dc < 4; ++dc) {
            const float* row = &WinS[wbuf][(wv * 4 + dc) * WIN];
#pragma unroll
            for (int k = 0; k < 3; ++k) {
                float v0 = row[li[k]];
                float v1 = row[li[k] + 1];
                sv[dc * 3 + k] = rw0[k] * v0 + rw1[k] * v1;
            }
        }
        unsigned ob[6];
#pragma unroll
        for (int j = 0; j < 6; ++j)
            ob[j] = pk2(sv[2 * j], sv[2 * j + 1]);   // lo=2j, hi=2j+1 (LE short order)
        unsigned* sp = reinterpret_cast<unsigned*>(&SlS[sbuf][lane * SLD + wv * 12]);
#pragma unroll
        for (int j = 0; j < 3; ++j)
            *reinterpret_cast<u32x2*>(sp + 2 * j) = (u32x2){ob[2 * j], ob[2 * j + 1]};
    };

    // ---- A-loads for chunk c (6 x bf16x8 from L2-hot wb) into persistent af ----
    auto loadA = [&](int c, bf16x8* af) {
#pragma unroll
        for (int ks = 0; ks < 3; ++ks)
#pragma unroll
            for (int mt = 0; mt < 2; ++mt)
                af[ks * 2 + mt] = *reinterpret_cast<const bf16x8*>(
                    wb + (size_t)(wv * 32 + mt * 16 + lr) * CK + c * 96 + ks * 32 + lq * 8);
    };

    // ---- MFMA with preloaded A-frags; B-frags from SlS[sbuf]; pure LDS+MFMA ----
    auto mfma_use = [&](const bf16x8* af, int sbuf) {
#pragma unroll
        for (int ks = 0; ks < 3; ++ks) {
            bf16x8 bfv[4];
#pragma unroll
            for (int nt = 0; nt < 4; ++nt)
                bfv[nt] = *reinterpret_cast<const bf16x8*>(
                    &SlS[sbuf][(nt * 16 + lr) * SLD + ks * 32 + lq * 8]);
            __builtin_amdgcn_s_setprio(1);
#pragma unroll
            for (int mt = 0; mt < 2; ++mt)
#pragma unroll
                for (int nt = 0; nt < 4; ++nt)
                    acc[mt][nt] = __builtin_amdgcn_mfma_f32_16x16x32_bf16(
                        af[ks * 2 + mt], bfv[nt], acc[mt][nt], 0, 0, 0);
            __builtin_amdgcn_s_setprio(0);
        }
    };

    bf16x8 afA[6];

    // ---- prologue: af(0) first (oldest, drained free), stage 0,1,2; wait S(0) ----
    loadA(0, afA);
    stage(0, 0);
    stage(1, 1);
    stage(2, 2);
    if (wv < 4) vmwait<4>(); else vmwait<2>();   // S(0)+af(0) landed; S(1),S(2) in flight
    __builtin_amdgcn_s_barrier();
    gather(0, 0);

    // ---- iter 0: S(1) landed (only S(1),S(2) outstanding) ----
    if (wv < 4) vmwait<2>(); else vmwait<1>();
    lgkm0();
    __builtin_amdgcn_s_barrier();
    gather(1, 1);
    mfma_use(afA, 0);
    __builtin_amdgcn_sched_barrier(0);
    loadA(1, afA);                   // af BEFORE stage: af-wait never drains stage
    __builtin_amdgcn_sched_barrier(0);
    stage(3, 0);

    // ---- iters 1..4: ensure S(c+1) (oldest) landed, keep af(c)+S(c+2) in flight ----
#define ITER_MID(c)                                                    \
    if (wv < 4) vmwait<8>(); else vmwait<7>();                         \
    lgkm0();                                                           \
    __builtin_amdgcn_s_barrier();                                      \
    gather(((c) + 1) % 3, ((c) + 1) & 1);                              \
    mfma_use(afA, (c) & 1);                                            \
    __builtin_amdgcn_sched_barrier(0);                                 \
    loadA((c) + 1, afA);                                               \
    __builtin_amdgcn_sched_barrier(0);                                 \
    stage((c) + 3, (c) % 3);

    ITER_MID(1)
    ITER_MID(2)
    ITER_MID(3)
    ITER_MID(4)
#undef ITER_MID

    // ---- iter 5: last full pattern minus stage (S(7) was staged at iter 4) ----
    if (wv < 4) vmwait<8>(); else vmwait<7>();
    lgkm0();
    __builtin_amdgcn_s_barrier();
    gather(0, 0);                    // chunk 6 -> Win[0], Sl[0]
    mfma_use(afA, 1);
    __builtin_amdgcn_sched_barrier(0);
    loadA(6, afA);

    // ---- iter 6: outstanding [S(7), af(6)]: ensure S(7) ----
    vmwait<6>();
    lgkm0();
    __builtin_amdgcn_s_barrier();
    gather(1, 1);                    // chunk 7 -> Win[1], Sl[1]
    mfma_use(afA, 0);
    __builtin_amdgcn_sched_barrier(0);
    loadA(7, afA);

    // ---- iter 7 ----
    lgkm0();
    __builtin_amdgcn_s_barrier();
    mfma_use(afA, 1);

    // ---- epilogue: D row = lq*4+reg (oc), col = lr (w) ----
    float* ob = out + ((size_t)b * OCH) * WLEN + wt * 64;
#pragma unroll
    for (int mt = 0; mt < 2; ++mt) {
#pragma unroll
        for (int r = 0; r < 4; ++r) {
            int row = wv * 32 + mt * 16 + lq * 4 + r;
            float bv = bias[row];
            float* orow = ob + (size_t)row * WLEN + lr;
#pragma unroll
            for (int nt = 0; nt < 4; ++nt)
                orow[nt * 16] = acc[mt][nt][r] + bv;
        }
    }
}

extern "C" void kernel_launch(void* const* d_in, const int* in_sizes, int n_in,
                              void* d_out, int out_size, void* d_ws, size_t ws_size,
                              hipStream_t stream) {
    const float* x    = (const float*)d_in[0];
    const float* w    = (const float*)d_in[1];
    const float* off  = (const float*)d_in[2];
    const float* msk  = (const float*)d_in[3];
    const float* bias = (const float*)d_in[4];
    float* out = (float*)d_out;
    short* wb  = (short*)d_ws;   // 384 KB bf16 weights

    wconv_kernel<<<768, 256, 0, stream>>>(w, wb);
    deform_fused_kernel<<<BATCH * 64, 512, 0, stream>>>(x, wb, off, msk, bias, out);
}

// Round 13
// 148.055 us; speedup vs baseline: 1.1054x; 1.1054x over previous
//
#include <hip/hip_runtime.h>

#define BATCH 16
#define CCH   256
#define WLEN  4096
#define OCH   256
#define KW    3
#define CK    768      // CCH*KW
#define WIN   96       // x-window floats per channel
#define CHUNK 32       // channels per K-chunk
#define NCHUNK 8       // CCH / CHUNK
#define SLD   104      // Sl row stride (shorts): 96 ck + 8 pad, keeps 16B align

typedef short bf16x8 __attribute__((ext_vector_type(8)));
typedef short bf16x4 __attribute__((ext_vector_type(4)));
typedef float f32x4  __attribute__((ext_vector_type(4)));

__device__ inline short f2bf(float f) {
    union { float f; unsigned u; } v; v.f = f;
    unsigned r = v.u + 0x7FFFu + ((v.u >> 16) & 1u);   // RNE
    return (short)(r >> 16);
}

__device__ inline void gl_lds16(const void* g, void* l) {
    __builtin_amdgcn_global_load_lds(
        (const __attribute__((address_space(1))) unsigned int*)g,
        (__attribute__((address_space(3))) unsigned int*)l, 16, 0, 0);
}

template<int N> __device__ inline void vmwait() {
    if constexpr (N == 0)      asm volatile("s_waitcnt vmcnt(0)" ::: "memory");
    else if constexpr (N == 1) asm volatile("s_waitcnt vmcnt(1)" ::: "memory");
    else if constexpr (N == 2) asm volatile("s_waitcnt vmcnt(2)" ::: "memory");
    else if constexpr (N == 4) asm volatile("s_waitcnt vmcnt(4)" ::: "memory");
    else if constexpr (N == 6) asm volatile("s_waitcnt vmcnt(6)" ::: "memory");
    else if constexpr (N == 7) asm volatile("s_waitcnt vmcnt(7)" ::: "memory");
    else if constexpr (N == 8) asm volatile("s_waitcnt vmcnt(8)" ::: "memory");
}
__device__ inline void lgkm0() { asm volatile("s_waitcnt lgkmcnt(0)" ::: "memory"); }

// ---------------- kernel 1: weight fp32 [256][768] -> bf16 FRAGMENT-ORDERED ----------------
// wbF[((c*3+ks)*16 + tile)*64 + lane][e] = A[tile*16 + (lane&15)][c*96 + ks*32 + (lane>>4)*8 + e]
// so the main kernel's A-fragment load is base + lane*16B: coalesced, 4 cache lines per
// wave-instruction instead of 16 (old row-major layout: 16 rows x 1536B stride = 16 lines).
__global__ void wconv_kernel(const float* __restrict__ w, short* __restrict__ wb) {
    int i    = blockIdx.x * 256 + threadIdx.x;   // 0..196607
    int e    = i & 7;
    int lane = (i >> 3) & 63;
    int tile = (i >> 9) & 15;
    int rest = i >> 13;                          // 0..23
    int ks   = rest % 3;
    int c    = rest / 3;                         // 0..7
    int row  = tile * 16 + (lane & 15);
    int ck   = c * 96 + ks * 32 + (lane >> 4) * 8 + e;
    wb[i] = f2bf(w[row * CK + ck]);
}

// ---------------- fused kernel v14: v11 + fragment-ordered A-loads (TA relief) ----------------
// EXACT v11 choreography (71.6 us best). One change: loadA reads the fragment-ordered wbF
// at base + lane*16 (coalesced). TA line-transactions per CU-slot drop ~5.4k -> ~1.4k;
// explains v8's +44us (doubled A-loads saturated TA). LDS pipe (~77% busy) becomes the bound.
__global__ __launch_bounds__(512, 4)
void deform_fused_kernel(const float* __restrict__ x,
                         const short* __restrict__ wb,
                         const float* __restrict__ off,
                         const float* __restrict__ msk,
                         const float* __restrict__ bias,
                         float* __restrict__ out) {
    __shared__ float WinS[3][CHUNK * WIN];   // 3 x 12288 B: chunk windows
    __shared__ short SlS[2][64 * SLD];       // 2 x 13312 B: gathered B-tile [w][96ck]

    const int t      = threadIdx.x;
    const int b      = blockIdx.x >> 6;
    const int wt     = blockIdx.x & 63;
    const int lane   = t & 63;
    const int wv     = t >> 6;
    const int lr     = lane & 15;
    const int lq     = lane >> 4;
    const int wstart = wt * 64 - 16;
    const int wg     = wt * 64 + lane;

    // ---- per-lane sampling params (identical math to validated kernel) ----
    int   li[3];
    float rw0[3], rw1[3];
#pragma unroll
    for (int k = 0; k < 3; ++k) {
        float o  = off[b * (KW * WLEN) + k * WLEN + wg];
        float m  = msk[b * (KW * WLEN) + k * WLEN + wg];
        float p  = (float)(wg - 1 + k) + o;
        float pf = floorf(p);
        float w1 = p - pf;
        int i0 = (int)pf;
        int i1 = i0 + 1;
        bool v0 = (i0 >= 0) & (i0 < WLEN);
        bool v1 = (i1 >= 0) & (i1 < WLEN);
        li[k]  = min(max(i0 - wstart, 0), WIN - 2);   // row[li], row[li+1] both in-window
        rw0[k] = v0 ? m * (1.0f - w1) : 0.0f;
        rw1[k] = v1 ? m * w1 : 0.0f;
    }

    const float* xb = x + (size_t)b * CCH * WLEN;

    // ---- staging source offsets (lane-static): 768 float4 slots per chunk ----
    const int sA = t;
    const int chA = sA / 24, oA = sA - chA * 24;
    const int jA  = min(max(wstart + oA * 4, 0), WLEN - 4);
    const int offA = chA * WLEN + jA;
    const int sB = 512 + t;
    const int chB = sB / 24, oB = sB - chB * 24;
    const int jB  = min(max(wstart + oB * 4, 0), WLEN - 4);
    const int offB = chB * WLEN + jB;

    f32x4 acc[2][4];
#pragma unroll
    for (int i = 0; i < 2; ++i)
#pragma unroll
        for (int j = 0; j < 4; ++j)
            acc[i][j] = (f32x4){0.f, 0.f, 0.f, 0.f};

    // ---- stage chunk c's windows into WinS[bufsel] (waves 0-3: 2 DMA, 4-7: 1 DMA) ----
    auto stage = [&](int c, int bufsel) {
        const float* src = xb + (size_t)c * CHUNK * WLEN;
        gl_lds16(src + offA, &WinS[bufsel][wv * 256]);
        if (wv < 4) gl_lds16(src + offB, &WinS[bufsel][2048 + wv * 256]);
    };

    // ---- gather: wave wv samples its 4 channels from WinS[wbuf] -> SlS[sbuf] ----
    auto gather = [&](int wbuf, int sbuf) {
        short obuf[12];
#pragma unroll
        for (int dc = 0; dc < 4; ++dc) {
            const float* row = &WinS[wbuf][(wv * 4 + dc) * WIN];
#pragma unroll
            for (int k = 0; k < 3; ++k) {
                float v0 = row[li[k]];
                float v1 = row[li[k] + 1];
                obuf[dc * 3 + k] = f2bf(rw0[k] * v0 + rw1[k] * v1);
            }
        }
        short* sp = &SlS[sbuf][lane * SLD + wv * 12];   // cols [wv*12, wv*12+12)
#pragma unroll
        for (int j = 0; j < 3; ++j)
            *reinterpret_cast<bf16x4*>(sp + j * 4) =
                *reinterpret_cast<const bf16x4*>(&obuf[j * 4]);
    };

    // ---- A-loads for chunk c: fragment-ordered, base + lane*16B (coalesced) ----
    auto loadA = [&](int c, bf16x8* af) {
#pragma unroll
        for (int ks = 0; ks < 3; ++ks)
#pragma unroll
            for (int mt = 0; mt < 2; ++mt)
                af[ks * 2 + mt] = *reinterpret_cast<const bf16x8*>(
                    wb + ((size_t)((c * 3 + ks) * 16 + wv * 2 + mt) * 64 + lane) * 8);
    };

    // ---- MFMA with preloaded A-frags; B-frags from SlS[sbuf]; pure LDS+MFMA ----
    auto mfma_use = [&](const bf16x8* af, int sbuf) {
#pragma unroll
        for (int ks = 0; ks < 3; ++ks) {
            bf16x8 bfv[4];
#pragma unroll
            for (int nt = 0; nt < 4; ++nt)
                bfv[nt] = *reinterpret_cast<const bf16x8*>(
                    &SlS[sbuf][(nt * 16 + lr) * SLD + ks * 32 + lq * 8]);
            __builtin_amdgcn_s_setprio(1);
#pragma unroll
            for (int mt = 0; mt < 2; ++mt)
#pragma unroll
                for (int nt = 0; nt < 4; ++nt)
                    acc[mt][nt] = __builtin_amdgcn_mfma_f32_16x16x32_bf16(
                        af[ks * 2 + mt], bfv[nt], acc[mt][nt], 0, 0, 0);
            __builtin_amdgcn_s_setprio(0);
        }
    };

    bf16x8 afA[6];

    // ---- prologue: af(0) first (oldest, drained free), stage 0,1,2; wait S(0) ----
    loadA(0, afA);
    stage(0, 0);
    stage(1, 1);
    stage(2, 2);
    if (wv < 4) vmwait<4>(); else vmwait<2>();   // S(0)+af(0) landed; S(1),S(2) in flight
    __builtin_amdgcn_s_barrier();
    gather(0, 0);

    // ---- iter 0: S(1) landed (only S(1),S(2) outstanding) ----
    if (wv < 4) vmwait<2>(); else vmwait<1>();
    lgkm0();
    __builtin_amdgcn_s_barrier();
    gather(1, 1);
    mfma_use(afA, 0);
    __builtin_amdgcn_sched_barrier(0);
    loadA(1, afA);                   // af BEFORE stage: af-wait never drains stage
    __builtin_amdgcn_sched_barrier(0);
    stage(3, 0);

    // ---- iters 1..4: ensure S(c+1) (oldest) landed, keep af(c)+S(c+2) in flight ----
#define ITER_MID(c)                                                    \
    if (wv < 4) vmwait<8>(); else vmwait<7>();                         \
    lgkm0();                                                           \
    __builtin_amdgcn_s_barrier();                                      \
    gather(((c) + 1) % 3, ((c) + 1) & 1);                              \
    mfma_use(afA, (c) & 1);                                            \
    __builtin_amdgcn_sched_barrier(0);                                 \
    loadA((c) + 1, afA);                                               \
    __builtin_amdgcn_sched_barrier(0);                                 \
    stage((c) + 3, (c) % 3);

    ITER_MID(1)
    ITER_MID(2)
    ITER_MID(3)
    ITER_MID(4)
#undef ITER_MID

    // ---- iter 5: last full pattern minus stage (S(7) was staged at iter 4) ----
    if (wv < 4) vmwait<8>(); else vmwait<7>();
    lgkm0();
    __builtin_amdgcn_s_barrier();
    gather(0, 0);                    // chunk 6 -> Win[0], Sl[0]
    mfma_use(afA, 1);
    __builtin_amdgcn_sched_barrier(0);
    loadA(6, afA);

    // ---- iter 6: outstanding [S(7), af(6)]: ensure S(7) ----
    vmwait<6>();
    lgkm0();
    __builtin_amdgcn_s_barrier();
    gather(1, 1);                    // chunk 7 -> Win[1], Sl[1]
    mfma_use(afA, 0);
    __builtin_amdgcn_sched_barrier(0);
    loadA(7, afA);

    // ---- iter 7 ----
    lgkm0();
    __builtin_amdgcn_s_barrier();
    mfma_use(afA, 1);

    // ---- epilogue: D row = lq*4+reg (oc), col = lr (w) ----
    float* ob = out + ((size_t)b * OCH) * WLEN + wt * 64;
#pragma unroll
    for (int mt = 0; mt < 2; ++mt) {
#pragma unroll
        for (int r = 0; r < 4; ++r) {
            int row = wv * 32 + mt * 16 + lq * 4 + r;
            float bv = bias[row];
            float* orow = ob + (size_t)row * WLEN + lr;
#pragma unroll
            for (int nt = 0; nt < 4; ++nt)
                orow[nt * 16] = acc[mt][nt][r] + bv;
        }
    }
}

extern "C" void kernel_launch(void* const* d_in, const int* in_sizes, int n_in,
                              void* d_out, int out_size, void* d_ws, size_t ws_size,
                              hipStream_t stream) {
    const float* x    = (const float*)d_in[0];
    const float* w    = (const float*)d_in[1];
    const float* off  = (const float*)d_in[2];
    const float* msk  = (const float*)d_in[3];
    const float* bias = (const float*)d_in[4];
    float* out = (float*)d_out;
    short* wb  = (short*)d_ws;   // 384 KB bf16 weights, fragment-ordered

    wconv_kernel<<<768, 256, 0, stream>>>(w, wb);
    deform_fused_kernel<<<BATCH * 64, 512, 0, stream>>>(x, wb, off, msk, bias, out);
}